// Round 8
// baseline (1509.283 us; speedup 1.0000x reference)
//
#include <hip/hip_runtime.h>
#include <hip/hip_bf16.h>

#define NUMC 2048

typedef short bf16x8 __attribute__((ext_vector_type(8)));
typedef float f32x4 __attribute__((ext_vector_type(4)));
typedef int i32x8 __attribute__((ext_vector_type(8)));

__device__ __forceinline__ unsigned short f2bf(float f) {
  unsigned int u = __float_as_uint(f);
  u = u + 0x7fffu + ((u >> 16) & 1u);
  return (unsigned short)(u >> 16);
}
__device__ __forceinline__ float bf2f(unsigned short s) {
  return __uint_as_float(((unsigned int)s) << 16);
}
__device__ __forceinline__ float sigm(float x) {
  return __fdividef(1.f, 1.f + __expf(-x));
}
__device__ __forceinline__ float tanh_(float x) {
  float ax = fabsf(x);
  float s = __expf(-2.f * ax);
  float ta = __fdividef(1.f - s, 1.f + s);
  return copysignf(ta, x);
}
__device__ __forceinline__ unsigned int pack2(unsigned short a, unsigned short b) {
  return (unsigned int)a | ((unsigned int)b << 16);
}
// async 16B/lane global->LDS (lds dest = wave-uniform base + lane*16)
__device__ __forceinline__ void gll16(const void* g, void* lds) {
  __builtin_amdgcn_global_load_lds(
      (const __attribute__((address_space(1))) unsigned int*)g,
      (__attribute__((address_space(3))) unsigned int*)lds, 16, 0, 0);
}

// ---- pack B into linear MFMA slabs: Bp[((ks*Ng + ng)*64 + l)*8 + j] =
//      bf16(W[(ng*16 + (l&15))*320 + ks*32 + (l>>4)*8 + j]);  ks=0..9 (K=320)
__global__ void k_pack_b(const float* __restrict__ W, unsigned short* __restrict__ Bp,
                         int Nmask, int logNg) {
  int e = blockIdx.x * 256 + threadIdx.x;  // N*320 total
  int j = e & 7;
  int l = (e >> 3) & 63;
  int ng = (e >> 9) & Nmask;
  int ks = e >> (9 + logNg);
  int n = ng * 16 + (l & 15);
  int k = ks * 32 + (l >> 4) * 8 + j;
  Bp[e] = f2bf(W[n * 320 + k]);
}

// ---- per-gate-row scale for fp8 quantization of W_hh
__global__ void k_rowmax(const float* __restrict__ Whh, float* __restrict__ fs) {
  int row = blockIdx.x;
  int l = threadIdx.x;  // 64
  float m = 0.f;
#pragma unroll
  for (int i = 0; i < 4; ++i) m = fmaxf(m, fabsf(Whh[row * 256 + i * 64 + l]));
#pragma unroll
  for (int off = 32; off > 0; off >>= 1) m = fmaxf(m, __shfl_xor(m, off));
  if (l == 0) fs[row] = (m > 0.f ? m : 1.f) * (1.f / 192.f);
}

// ---- pack W_hh into fp8 e4m3 fragments for mfma_scale 16x16x128:
// frag = ((w*2+nt)*4+g)*2+kt ; lane l holds 32 bytes: k = kt*128 + (l>>4)*32 + 0..31
__global__ void k_pack_whh_mx(const float* __restrict__ Whh, const float* __restrict__ fs,
                              long long* __restrict__ P) {
  int e = blockIdx.x * 256 + threadIdx.x;  // 8192 lane-slots
  int l = e & 63;
  int frag = e >> 6;
  int kt = frag & 1;
  int g = (frag >> 1) & 3;
  int nt = (frag >> 3) & 1;
  int w = frag >> 4;
  int gr = g * 256 + w * 32 + nt * 16 + (l & 15);
  int k0 = kt * 128 + (l >> 4) * 32;
  float inv = __fdividef(1.f, fs[gr]);
#pragma unroll
  for (int q = 0; q < 4; ++q) {
    unsigned long long v = 0;
#pragma unroll
    for (int jj = 0; jj < 4; ++jj) {
      float w0 = Whh[gr * 256 + k0 + q * 8 + 2 * jj] * inv;
      float w1 = Whh[gr * 256 + k0 + q * 8 + 2 * jj + 1] * inv;
      int pk = __builtin_amdgcn_cvt_pk_fp8_f32(w0, w1, 0, 0);
      v |= (unsigned long long)(unsigned)(pk & 0xffff) << (16 * jj);
    }
    P[(size_t)e * 4 + q] = (long long)v;
  }
}

// ---- theta = bf16(E[x]*Cct), C2 = bf16(Cct_shifted), packed combos
__global__ void k_theta(const int* __restrict__ q, const int* __restrict__ r,
                        const int* __restrict__ rg_, const int* __restrict__ sg_,
                        const int* __restrict__ pc_, const int* __restrict__ srg_,
                        const int* __restrict__ ssg_, const int* __restrict__ spc_,
                        const float* __restrict__ E, const float* __restrict__ Wc,
                        unsigned short* __restrict__ theta, unsigned short* __restrict__ C2,
                        int* __restrict__ combo, int* __restrict__ combo2) {
  int tid = threadIdx.x;
  int row = blockIdx.x * 8 + (tid >> 5);
  int u0 = (tid & 31) * 8;
  int x = q[row] + NUMC * r[row];
  int rg = rg_[row], sg = sg_[row], pc = pc_[row];
  int g1 = srg_[row], g2 = ssg_[row], g3 = spc_[row];
  const float* e = E + (size_t)x * 256 + u0;
  unsigned short tv[8], cv[8];
#pragma unroll
  for (int i = 0; i < 8; ++i) {
    const float* wr = Wc + (size_t)(u0 + i) * 64;
    float cct = wr[rg] + wr[16 + sg] + wr[32 + pc];
    float cc2 = wr[g1] + wr[16 + g2] + wr[32 + g3];
    tv[i] = f2bf(e[i] * cct);
    cv[i] = f2bf(cc2);
  }
  uint4 tvec = {pack2(tv[0], tv[1]), pack2(tv[2], tv[3]), pack2(tv[4], tv[5]), pack2(tv[6], tv[7])};
  uint4 cvec = {pack2(cv[0], cv[1]), pack2(cv[2], cv[3]), pack2(cv[4], cv[5]), pack2(cv[6], cv[7])};
  *(uint4*)(theta + (size_t)row * 256 + u0) = tvec;
  *(uint4*)(C2 + (size_t)row * 256 + u0) = cvec;
  if ((tid & 31) == 0) {
    combo[row] = (rg * 16 + sg) * 32 + pc;
    combo2[row] = (g1 * 16 + g2) * 32 + g3;
  }
}

__device__ __forceinline__ uint4 onehot8(int k0, int rg, int sg, int pc) {
  unsigned vv[8];
#pragma unroll
  for (int j = 0; j < 8; ++j) {
    int k = k0 + j;
    vv[j] = (k == rg || k == sg || k == pc) ? 0x3F80u : 0u;
  }
  uint4 rr;
  rr.x = vv[0] | (vv[1] << 16);
  rr.y = vv[2] | (vv[3] << 16);
  rr.z = vv[4] | (vv[5] << 16);
  rr.w = vv[6] | (vv[7] << 16);
  return rr;
}

// ---- 128x128xK=320 bf16 MFMA GEMM, m97-style global_load_lds staging.
// K 0..255 async-staged from A; K 256..319 synthesized one-hot (ds_write).
// XCD-aware remap: all N-tiles of one M-panel land on one XCD.
// MODE 0: xg = [A|ct]*B^T + b_ih + b_hh -> bf16.  MODE 1: y = sigmoid(..+b_out) -> f32
template <int NTOT, int MODE, int LOGGX>
__global__ __launch_bounds__(256) void k_gemm(
    const unsigned short* __restrict__ A, const unsigned short* __restrict__ Bp,
    const int* __restrict__ combo, const float* __restrict__ bias1,
    const float* __restrict__ bias2, void* __restrict__ Out) {
  __shared__ __align__(16) unsigned short As[4096];  // 8 slabs [lane64][8]
  __shared__ __align__(16) unsigned short Bs[4096];
  const int tid = threadIdx.x;
  const int w = tid >> 6, l = tid & 63;
  const int wm = w >> 1, wn = w & 1;
  constexpr int NG = NTOT / 16;

  int id = blockIdx.y * (1 << LOGGX) + blockIdx.x;
  int Nbase = ((id >> 3) & ((1 << LOGGX) - 1)) * 128;
  int Mbase = ((((id >> (3 + LOGGX)) << 3) | (id & 7))) * 128;

  f32x4 acc[4][4];
#pragma unroll
  for (int i = 0; i < 4; ++i)
#pragma unroll
    for (int j = 0; j < 4; ++j) acc[i][j] = (f32x4){0.f, 0.f, 0.f, 0.f};

  // staging addresses: wave w owns slabs 2w, 2w+1 of both A and B
  unsigned short* AsW = &As[(2 * w) * 512];
  unsigned short* BsW = &Bs[(2 * w) * 512];
  const unsigned short* gA0 = A + (size_t)(Mbase + (2 * w) * 16 + (l & 15)) * 256 + (l >> 4) * 8;
  const unsigned short* gA1 = gA0 + 16 * 256;
  const unsigned short* gB0 = Bp + ((size_t)(Nbase / 16 + 2 * w) * 64 + l) * 8;
  const unsigned short* gB1 = gB0 + 64 * 8;

  // one-hot synth params (K tail)
  const int arow = tid >> 1;
  const int agp = (tid & 1) * 2;
  const int a_ch = arow >> 4;
  const int a_ls0 = (arow & 15) | (agp << 4);
  const int a_ls1 = (arow & 15) | ((agp + 1) << 4);
  const int cmb = combo[Mbase + arow];
  const int rg = cmb >> 9, sg = 16 + ((cmb >> 5) & 15), pc = 32 + (cmb & 31);

  for (int ks = 0; ks < 10; ++ks) {
    __syncthreads();  // all waves done reading previous K-step
    if (ks < 8) {
      gll16(gA0, AsW);
      gll16(gA1, AsW + 512);
      gA0 += 32;
      gA1 += 32;
    } else {
      int k0 = (ks - 8) * 32 + agp * 8;
      uint4 av0 = onehot8(k0, rg, sg, pc);
      uint4 av1 = onehot8(k0 + 8, rg, sg, pc);
      *(uint4*)&As[(a_ch * 64 + a_ls0) * 8] = av0;
      *(uint4*)&As[(a_ch * 64 + a_ls1) * 8] = av1;
    }
    gll16(gB0, BsW);
    gll16(gB1, BsW + 512);
    gB0 += (size_t)NG * 512;
    gB1 += (size_t)NG * 512;
    __syncthreads();  // compiler drains vmcnt/lgkmcnt before s_barrier
    bf16x8 bfr[4];
#pragma unroll
    for (int ni = 0; ni < 4; ++ni)
      bfr[ni] = *(const bf16x8*)&Bs[((wn * 4 + ni) * 64 + l) * 8];
#pragma unroll
    for (int mi = 0; mi < 4; ++mi) {
      bf16x8 af = *(const bf16x8*)&As[((wm * 4 + mi) * 64 + l) * 8];
#pragma unroll
      for (int ni = 0; ni < 4; ++ni)
        acc[mi][ni] = __builtin_amdgcn_mfma_f32_16x16x32_bf16(af, bfr[ni], acc[mi][ni], 0, 0, 0);
    }
  }

  int lh = l >> 4, col = l & 15;
  float badd[4];
#pragma unroll
  for (int ni = 0; ni < 4; ++ni) {
    int gcol = Nbase + wn * 64 + ni * 16 + col;
    badd[ni] = bias1[gcol] + (MODE == 0 ? bias2[gcol] : 0.f);
  }
#pragma unroll
  for (int mi = 0; mi < 4; ++mi) {
    int grow0 = Mbase + wm * 64 + mi * 16 + lh * 4;
#pragma unroll
    for (int rr = 0; rr < 4; ++rr) {
      int grow = grow0 + rr;
#pragma unroll
      for (int ni = 0; ni < 4; ++ni) {
        int gcol = Nbase + wn * 64 + ni * 16 + col;
        float v = acc[mi][ni][rr] + badd[ni];
        if (MODE == 0) {
          ((unsigned short*)Out)[(size_t)grow * NTOT + gcol] = f2bf(v);
        } else {
          ((float*)Out)[(size_t)grow * NTOT + gcol] = sigm(v);
        }
      }
    }
  }
}

// ---- LSTM: 128 independent blocks x 2 batch rows; all 1024 gates per block.
// W_hh fp8 in VGPRs (128/lane), consumed by mfma_scale_f32_16x16x128_f8f6f4 with
// identity e8m0 scales (per-gate fs applied in epilogue). Full epilogue
// redistribution: permlane32_swap (nt) + shfl_xor16 (row) -> ONE h-output/lane.
__global__ __launch_bounds__(512, 1) void k_lstm(
    const unsigned short* __restrict__ xg, const unsigned short* __restrict__ C2,
    const long long* __restrict__ Wq, const float* __restrict__ fs,
    unsigned short* __restrict__ h2) {
  // hq: [2 buffers][16 rows][264 bytes] (8-byte row pad -> conflict-light reads)
  __shared__ __align__(16) char hq[2][4224];
  const int tid = threadIdx.x;
  const int w = tid >> 6, l = tid & 63;
  const int col = l & 15, lh = l >> 4;
  const int blk = blockIdx.x;  // 128 blocks

  // 16 fragments x 8 VGPR = 128 registers of fp8 weights per lane
  i32x8 wreg[2][4][2];
#pragma unroll
  for (int nt = 0; nt < 2; ++nt)
#pragma unroll
    for (int g = 0; g < 4; ++g)
#pragma unroll
      for (int kt = 0; kt < 2; ++kt)
        wreg[nt][g][kt] =
            ((const i32x8*)Wq)[(((w * 2 + nt) * 4 + g) * 2 + kt) * 64 + l];

  // post-redistribution assignment: one (row, unit) per lane
  const int u = w * 32 + ((l >> 5) << 4) + col;  // lanes>=32 take nt=1 sub-tile
  const int row = (l >> 4) & 1;                  // lanes 16-31 / 48-63 take row 1
  float fsl[4];
#pragma unroll
  for (int g = 0; g < 4; ++g) fsl[g] = fs[g * 256 + u];

  // zero both hq buffers (8448 B): rows 2..15 stay zero forever (M=16 tile, 2 valid rows)
  {
    uint4 zz = {0u, 0u, 0u, 0u};
    ((uint4*)hq)[tid] = zz;
    if (tid < 16) ((uint4*)hq)[512 + tid] = zz;
  }

  const unsigned bg = (unsigned)(blk * 2 + row);
  unsigned xb = (bg << 19) + (unsigned)u;  // (bg*512 + t)*1024 + u at t=0
  unsigned cb = (bg << 17) + (unsigned)u;  // (bg*512 + t)*256  + u at t=0

  unsigned short xcur[4], ccur;
#pragma unroll
  for (int g = 0; g < 4; ++g) xcur[g] = xg[xb + g * 256];
  ccur = C2[cb];
  xb += 1024;  // -> t=1

  __syncthreads();

  float cst = 0.f;

#pragma unroll 1
  for (int t = 0; t < 512; ++t) {
    const int pb = t & 1;
    // prefetch t+1 (at t=511 reads harmlessly into dead d_out space)
    unsigned short xnxt[4], cnxt;
#pragma unroll
    for (int g = 0; g < 4; ++g) xnxt[g] = xg[xb + g * 256];
    cnxt = C2[cb + 256];

    f32x4 acc[2][4];
#pragma unroll
    for (int nt = 0; nt < 2; ++nt)
#pragma unroll
      for (int g = 0; g < 4; ++g) acc[nt][g] = (f32x4){0.f, 0.f, 0.f, 0.f};
#pragma unroll
    for (int kt = 0; kt < 2; ++kt) {
      int ab = col * 264 + kt * 128 + lh * 32;
      uint4 a0 = *(const uint4*)&hq[pb][ab];
      uint4 a1 = *(const uint4*)&hq[pb][ab + 16];
      i32x8 av;
      av[0] = (int)a0.x; av[1] = (int)a0.y; av[2] = (int)a0.z; av[3] = (int)a0.w;
      av[4] = (int)a1.x; av[5] = (int)a1.y; av[6] = (int)a1.z; av[7] = (int)a1.w;
#pragma unroll
      for (int nt = 0; nt < 2; ++nt)
#pragma unroll
        for (int g = 0; g < 4; ++g)
          acc[nt][g] = __builtin_amdgcn_mfma_scale_f32_16x16x128_f8f6f4(
              av, wreg[nt][g][kt], acc[nt][g], 0, 0, 0, 0x7F7F7F7F, 0, 0x7F7F7F7F);
    }

    // redistribute to 1 gate-quad per lane:
    // stage 1 (permlane32_swap): lanes<32 nt0, lanes>=32 nt1 (rows in regs rr=0,1)
    // stage 2 (shfl_xor 16 + select): odd 16-lane groups take row 1
    float p[4];
#pragma unroll
    for (int g = 0; g < 4; ++g) {
      unsigned a00 = __float_as_uint(acc[0][g][0]);
      unsigned a10 = __float_as_uint(acc[1][g][0]);
      unsigned a01 = __float_as_uint(acc[0][g][1]);
      unsigned a11 = __float_as_uint(acc[1][g][1]);
      auto r0p = __builtin_amdgcn_permlane32_swap(a00, a10, false, false);
      auto r1p = __builtin_amdgcn_permlane32_swap(a01, a11, false, false);
      float m0 = __uint_as_float(r0p[0]);
      float m1 = __uint_as_float(r1p[0]);
      float s1 = __shfl_xor(m1, 16);
      p[g] = row ? s1 : m0;
    }

    float iv = sigm(p[0] * fsl[0] + bf2f(xcur[0]));
    float fv = sigm(p[1] * fsl[1] + bf2f(xcur[1]));
    float gv = tanh_(p[2] * fsl[2] + bf2f(xcur[2]));
    float ov = sigm(p[3] * fsl[3] + bf2f(xcur[3]));
    float cv = fv * cst + iv * gv;
    cst = cv;
    float hv = ov * tanh_(cv);
    h2[cb] = f2bf(hv * bf2f(ccur));
    {
      int pk = __builtin_amdgcn_cvt_pk_fp8_f32(hv, hv, 0, 0);
      hq[pb ^ 1][row * 264 + u] = (char)(pk & 255);
    }
#pragma unroll
    for (int g = 0; g < 4; ++g) xcur[g] = xnxt[g];
    ccur = cnxt;
    xb += 1024;
    cb += 256;
    __syncthreads();
  }
}

extern "C" void kernel_launch(void* const* d_in, const int* in_sizes, int n_in,
                              void* d_out, int out_size, void* d_ws, size_t ws_size,
                              hipStream_t stream) {
  const int* q = (const int*)d_in[0];
  const int* r = (const int*)d_in[1];
  const int* rg = (const int*)d_in[2];
  const int* sg = (const int*)d_in[3];
  const int* pc = (const int*)d_in[4];
  const int* srg = (const int*)d_in[5];
  const int* ssg = (const int*)d_in[6];
  const int* spc = (const int*)d_in[7];
  const float* E = (const float*)d_in[8];
  const float* Wc = (const float*)d_in[9];
  const float* Wih = (const float*)d_in[10];
  const float* Whh = (const float*)d_in[11];
  const float* bih = (const float*)d_in[12];
  const float* bhh = (const float*)d_in[13];
  const float* Wout = (const float*)d_in[14];
  const float* bout = (const float*)d_in[15];

  char* ws = (char*)d_ws;
  unsigned short* h2 = (unsigned short*)(ws);                // 64 MB
  unsigned short* Bpih = (unsigned short*)(ws + 67108864);   // 640 KB
  unsigned short* Bpout = (unsigned short*)(ws + 67764224);  // 1.25 MB
  long long* Wq = (long long*)(ws + 69074944);               // 256 KB
  float* fs = (float*)(ws + 69337088);                       // 4 KB
  int* combo = (int*)(ws + 69341184);                        // 512 KB
  int* combo2 = (int*)(ws + 69865472);                       // 512 KB (end 70389760)

  char* dout = (char*)d_out;
  unsigned short* xg = (unsigned short*)dout;                    // 256 MB (dead until final GEMM)
  unsigned short* theta = (unsigned short*)(dout + 268435456);   // 64 MB
  unsigned short* C2 = (unsigned short*)(dout + 335544320);      // 64 MB

  k_rowmax<<<1024, 64, 0, stream>>>(Whh, fs);
  k_pack_whh_mx<<<32, 256, 0, stream>>>(Whh, fs, Wq);
  k_pack_b<<<1280, 256, 0, stream>>>(Wih, Bpih, 63, 6);
  k_pack_b<<<2560, 256, 0, stream>>>(Wout, Bpout, 127, 7);
  k_theta<<<16384, 256, 0, stream>>>(q, r, rg, sg, pc, srg, ssg, spc, E, Wc, theta, C2, combo, combo2);
  k_gemm<1024, 0, 3><<<dim3(8, 1024), 256, 0, stream>>>(theta, Bpih, combo, bih, bhh, (void*)xg);
  k_lstm<<<128, 512, 0, stream>>>(xg, C2, Wq, fs, h2);
  k_gemm<2048, 1, 4><<<dim3(16, 1024), 256, 0, stream>>>(h2, Bpout, combo2, bout, nullptr, d_out);
}

// Round 9
// 1406.660 us; speedup vs baseline: 1.0730x; 1.0730x over previous
//
#include <hip/hip_runtime.h>
#include <hip/hip_bf16.h>

#define NUMC 2048

typedef short bf16x8 __attribute__((ext_vector_type(8)));
typedef float f32x4 __attribute__((ext_vector_type(4)));
typedef int i32x8 __attribute__((ext_vector_type(8)));

__device__ __forceinline__ unsigned short f2bf(float f) {
  unsigned int u = __float_as_uint(f);
  u = u + 0x7fffu + ((u >> 16) & 1u);
  return (unsigned short)(u >> 16);
}
__device__ __forceinline__ float bf2f(unsigned short s) {
  return __uint_as_float(((unsigned int)s) << 16);
}
__device__ __forceinline__ float sigm(float x) {
  return __fdividef(1.f, 1.f + __expf(-x));
}
__device__ __forceinline__ float tanh_(float x) {
  float ax = fabsf(x);
  float s = __expf(-2.f * ax);
  float ta = __fdividef(1.f - s, 1.f + s);
  return copysignf(ta, x);
}
__device__ __forceinline__ unsigned int pack2(unsigned short a, unsigned short b) {
  return (unsigned int)a | ((unsigned int)b << 16);
}
// async 16B/lane global->LDS (lds dest = wave-uniform base + lane*16)
__device__ __forceinline__ void gll16(const void* g, void* lds) {
  __builtin_amdgcn_global_load_lds(
      (const __attribute__((address_space(1))) unsigned int*)g,
      (__attribute__((address_space(3))) unsigned int*)lds, 16, 0, 0);
}

// ---- pack B into linear MFMA slabs: Bp[((ks*Ng + ng)*64 + l)*8 + j] =
//      bf16(W[(ng*16 + (l&15))*320 + ks*32 + (l>>4)*8 + j]);  ks=0..9 (K=320)
__global__ void k_pack_b(const float* __restrict__ W, unsigned short* __restrict__ Bp,
                         int Nmask, int logNg) {
  int e = blockIdx.x * 256 + threadIdx.x;  // N*320 total
  int j = e & 7;
  int l = (e >> 3) & 63;
  int ng = (e >> 9) & Nmask;
  int ks = e >> (9 + logNg);
  int n = ng * 16 + (l & 15);
  int k = ks * 32 + (l >> 4) * 8 + j;
  Bp[e] = f2bf(W[n * 320 + k]);
}

// ---- per-gate-row scale for fp8 quantization of W_hh
__global__ void k_rowmax(const float* __restrict__ Whh, float* __restrict__ fs) {
  int row = blockIdx.x;
  int l = threadIdx.x;  // 64
  float m = 0.f;
#pragma unroll
  for (int i = 0; i < 4; ++i) m = fmaxf(m, fabsf(Whh[row * 256 + i * 64 + l]));
#pragma unroll
  for (int off = 32; off > 0; off >>= 1) m = fmaxf(m, __shfl_xor(m, off));
  if (l == 0) fs[row] = (m > 0.f ? m : 1.f) * (1.f / 192.f);
}

// ---- pack W_hh into fp8 e4m3 fragments for mfma_scale 16x16x128:
// frag = ((w*2+nt)*4+g)*2+kt ; lane l holds 32 bytes: k = kt*128 + (l>>4)*32 + 0..31
__global__ void k_pack_whh_mx(const float* __restrict__ Whh, const float* __restrict__ fs,
                              long long* __restrict__ P) {
  int e = blockIdx.x * 256 + threadIdx.x;  // 8192 lane-slots
  int l = e & 63;
  int frag = e >> 6;
  int kt = frag & 1;
  int g = (frag >> 1) & 3;
  int nt = (frag >> 3) & 1;
  int w = frag >> 4;
  int gr = g * 256 + w * 32 + nt * 16 + (l & 15);
  int k0 = kt * 128 + (l >> 4) * 32;
  float inv = __fdividef(1.f, fs[gr]);
#pragma unroll
  for (int q = 0; q < 4; ++q) {
    unsigned long long v = 0;
#pragma unroll
    for (int jj = 0; jj < 4; ++jj) {
      float w0 = Whh[gr * 256 + k0 + q * 8 + 2 * jj] * inv;
      float w1 = Whh[gr * 256 + k0 + q * 8 + 2 * jj + 1] * inv;
      int pk = __builtin_amdgcn_cvt_pk_fp8_f32(w0, w1, 0, 0);
      v |= (unsigned long long)(unsigned)(pk & 0xffff) << (16 * jj);
    }
    P[(size_t)e * 4 + q] = (long long)v;
  }
}

// ---- theta = bf16(E[x]*Cct), C2 = bf16(Cct_shifted), packed combos
__global__ void k_theta(const int* __restrict__ q, const int* __restrict__ r,
                        const int* __restrict__ rg_, const int* __restrict__ sg_,
                        const int* __restrict__ pc_, const int* __restrict__ srg_,
                        const int* __restrict__ ssg_, const int* __restrict__ spc_,
                        const float* __restrict__ E, const float* __restrict__ Wc,
                        unsigned short* __restrict__ theta, unsigned short* __restrict__ C2,
                        int* __restrict__ combo, int* __restrict__ combo2) {
  int tid = threadIdx.x;
  int row = blockIdx.x * 8 + (tid >> 5);
  int u0 = (tid & 31) * 8;
  int x = q[row] + NUMC * r[row];
  int rg = rg_[row], sg = sg_[row], pc = pc_[row];
  int g1 = srg_[row], g2 = ssg_[row], g3 = spc_[row];
  const float* e = E + (size_t)x * 256 + u0;
  unsigned short tv[8], cv[8];
#pragma unroll
  for (int i = 0; i < 8; ++i) {
    const float* wr = Wc + (size_t)(u0 + i) * 64;
    float cct = wr[rg] + wr[16 + sg] + wr[32 + pc];
    float cc2 = wr[g1] + wr[16 + g2] + wr[32 + g3];
    tv[i] = f2bf(e[i] * cct);
    cv[i] = f2bf(cc2);
  }
  uint4 tvec = {pack2(tv[0], tv[1]), pack2(tv[2], tv[3]), pack2(tv[4], tv[5]), pack2(tv[6], tv[7])};
  uint4 cvec = {pack2(cv[0], cv[1]), pack2(cv[2], cv[3]), pack2(cv[4], cv[5]), pack2(cv[6], cv[7])};
  *(uint4*)(theta + (size_t)row * 256 + u0) = tvec;
  *(uint4*)(C2 + (size_t)row * 256 + u0) = cvec;
  if ((tid & 31) == 0) {
    combo[row] = (rg * 16 + sg) * 32 + pc;
    combo2[row] = (g1 * 16 + g2) * 32 + g3;
  }
}

__device__ __forceinline__ uint4 onehot8(int k0, int rg, int sg, int pc) {
  unsigned vv[8];
#pragma unroll
  for (int j = 0; j < 8; ++j) {
    int k = k0 + j;
    vv[j] = (k == rg || k == sg || k == pc) ? 0x3F80u : 0u;
  }
  uint4 rr;
  rr.x = vv[0] | (vv[1] << 16);
  rr.y = vv[2] | (vv[3] << 16);
  rr.z = vv[4] | (vv[5] << 16);
  rr.w = vv[6] | (vv[7] << 16);
  return rr;
}

// ---- 128x128xK=320 bf16 MFMA GEMM, m97-style global_load_lds staging.
// K 0..255 async-staged from A; K 256..319 synthesized one-hot (ds_write).
// XCD-aware remap: all N-tiles of one M-panel land on one XCD.
// MODE 0: xg = [A|ct]*B^T + b_ih + b_hh -> bf16.  MODE 1: y = sigmoid(..+b_out) -> f32
template <int NTOT, int MODE, int LOGGX>
__global__ __launch_bounds__(256) void k_gemm(
    const unsigned short* __restrict__ A, const unsigned short* __restrict__ Bp,
    const int* __restrict__ combo, const float* __restrict__ bias1,
    const float* __restrict__ bias2, void* __restrict__ Out) {
  __shared__ __align__(16) unsigned short As[4096];  // 8 slabs [lane64][8]
  __shared__ __align__(16) unsigned short Bs[4096];
  const int tid = threadIdx.x;
  const int w = tid >> 6, l = tid & 63;
  const int wm = w >> 1, wn = w & 1;
  constexpr int NG = NTOT / 16;

  int id = blockIdx.y * (1 << LOGGX) + blockIdx.x;
  int Nbase = ((id >> 3) & ((1 << LOGGX) - 1)) * 128;
  int Mbase = ((((id >> (3 + LOGGX)) << 3) | (id & 7))) * 128;

  f32x4 acc[4][4];
#pragma unroll
  for (int i = 0; i < 4; ++i)
#pragma unroll
    for (int j = 0; j < 4; ++j) acc[i][j] = (f32x4){0.f, 0.f, 0.f, 0.f};

  // staging addresses: wave w owns slabs 2w, 2w+1 of both A and B
  unsigned short* AsW = &As[(2 * w) * 512];
  unsigned short* BsW = &Bs[(2 * w) * 512];
  const unsigned short* gA0 = A + (size_t)(Mbase + (2 * w) * 16 + (l & 15)) * 256 + (l >> 4) * 8;
  const unsigned short* gA1 = gA0 + 16 * 256;
  const unsigned short* gB0 = Bp + ((size_t)(Nbase / 16 + 2 * w) * 64 + l) * 8;
  const unsigned short* gB1 = gB0 + 64 * 8;

  // one-hot synth params (K tail)
  const int arow = tid >> 1;
  const int agp = (tid & 1) * 2;
  const int a_ch = arow >> 4;
  const int a_ls0 = (arow & 15) | (agp << 4);
  const int a_ls1 = (arow & 15) | ((agp + 1) << 4);
  const int cmb = combo[Mbase + arow];
  const int rg = cmb >> 9, sg = 16 + ((cmb >> 5) & 15), pc = 32 + (cmb & 31);

  for (int ks = 0; ks < 10; ++ks) {
    __syncthreads();  // all waves done reading previous K-step
    if (ks < 8) {
      gll16(gA0, AsW);
      gll16(gA1, AsW + 512);
      gA0 += 32;
      gA1 += 32;
    } else {
      int k0 = (ks - 8) * 32 + agp * 8;
      uint4 av0 = onehot8(k0, rg, sg, pc);
      uint4 av1 = onehot8(k0 + 8, rg, sg, pc);
      *(uint4*)&As[(a_ch * 64 + a_ls0) * 8] = av0;
      *(uint4*)&As[(a_ch * 64 + a_ls1) * 8] = av1;
    }
    gll16(gB0, BsW);
    gll16(gB1, BsW + 512);
    gB0 += (size_t)NG * 512;
    gB1 += (size_t)NG * 512;
    __syncthreads();  // compiler drains vmcnt/lgkmcnt before s_barrier
    bf16x8 bfr[4];
#pragma unroll
    for (int ni = 0; ni < 4; ++ni)
      bfr[ni] = *(const bf16x8*)&Bs[((wn * 4 + ni) * 64 + l) * 8];
#pragma unroll
    for (int mi = 0; mi < 4; ++mi) {
      bf16x8 af = *(const bf16x8*)&As[((wm * 4 + mi) * 64 + l) * 8];
#pragma unroll
      for (int ni = 0; ni < 4; ++ni)
        acc[mi][ni] = __builtin_amdgcn_mfma_f32_16x16x32_bf16(af, bfr[ni], acc[mi][ni], 0, 0, 0);
    }
  }

  int lh = l >> 4, col = l & 15;
  float badd[4];
#pragma unroll
  for (int ni = 0; ni < 4; ++ni) {
    int gcol = Nbase + wn * 64 + ni * 16 + col;
    badd[ni] = bias1[gcol] + (MODE == 0 ? bias2[gcol] : 0.f);
  }
#pragma unroll
  for (int mi = 0; mi < 4; ++mi) {
    int grow0 = Mbase + wm * 64 + mi * 16 + lh * 4;
#pragma unroll
    for (int rr = 0; rr < 4; ++rr) {
      int grow = grow0 + rr;
#pragma unroll
      for (int ni = 0; ni < 4; ++ni) {
        int gcol = Nbase + wn * 64 + ni * 16 + col;
        float v = acc[mi][ni][rr] + badd[ni];
        if (MODE == 0) {
          ((unsigned short*)Out)[(size_t)grow * NTOT + gcol] = f2bf(v);
        } else {
          ((float*)Out)[(size_t)grow * NTOT + gcol] = sigm(v);
        }
      }
    }
  }
}

// ---- LSTM: 256 independent blocks x 1 batch row; all 1024 gates per block.
// W_hh fp8 in VGPRs (128/lane), mfma_scale 16x16x128 with identity e8m0 scales.
// NO per-step acc reset: acc carries running sum S_t; epilogue uses p = S_t - S_{t-1}.
// Gate-level spread: lanes 0-15/32-47 compute i,f; lanes 16-31/48-63 compute g,o
// (branchless parameterized activation A/(1+e^{-s x})+B); combine via shfl_xor(16).
__global__ __launch_bounds__(512, 1) void k_lstm(
    const unsigned short* __restrict__ xg, const unsigned short* __restrict__ C2,
    const long long* __restrict__ Wq, const float* __restrict__ fs,
    unsigned short* __restrict__ h2) {
  // hq: [2 buffers][16 rows][264 bytes]; only row 0 valid, rows 1..15 stay zero
  __shared__ __align__(16) char hq[2][4224];
  const int tid = threadIdx.x;
  const int w = tid >> 6, l = tid & 63;
  const int col = l & 15;
  const int half = (l >> 4) & 1;  // 0: i,f lanes   1: g,o lanes
  const int ntsel = l >> 5;
  const int blk = blockIdx.x;  // 256 blocks

  // 16 fragments x 8 VGPR = 128 registers of fp8 weights per lane
  i32x8 wreg[2][4][2];
#pragma unroll
  for (int nt = 0; nt < 2; ++nt)
#pragma unroll
    for (int g = 0; g < 4; ++g)
#pragma unroll
      for (int kt = 0; kt < 2; ++kt)
        wreg[nt][g][kt] =
            ((const i32x8*)Wq)[(((w * 2 + nt) * 4 + g) * 2 + kt) * 64 + l];

  const int u = w * 32 + ntsel * 16 + col;  // this lane's unit
  // this lane's two gates: ga = half*2, gb = half*2+1
  const float fsa = fs[(half * 2 + 0) * 256 + u];
  const float fsb = fs[(half * 2 + 1) * 256 + u];
  // activation params for ga: sigm (A=1,B=0,s=1) on i-lanes, tanh (A=2,B=-1,s=2) on g-lanes
  const float AA = half ? 2.f : 1.f;
  const float BB = half ? -1.f : 0.f;
  const float SS = half ? 2.f : 1.f;

  // zero both hq buffers (8448 B)
  {
    uint4 zz = {0u, 0u, 0u, 0u};
    ((uint4*)hq)[tid] = zz;
    if (tid < 16) ((uint4*)hq)[512 + tid] = zz;
  }

  const unsigned bg = (unsigned)blk;
  unsigned xb = (bg << 19) + (unsigned)((half * 2) * 256 + u);  // + t*1024
  unsigned cb = (bg << 17) + (unsigned)u;                       // + t*256

  unsigned short xac = xg[xb], xbc = xg[xb + 256];
  unsigned short cc = C2[cb];  // used by g,o lanes only
  xb += 1024;                  // -> t=1

  __syncthreads();

  float cst = 0.f;
  float SoldA = 0.f, SoldB = 0.f;
  f32x4 acc[2][4];
#pragma unroll
  for (int nt = 0; nt < 2; ++nt)
#pragma unroll
    for (int g = 0; g < 4; ++g) acc[nt][g] = (f32x4){0.f, 0.f, 0.f, 0.f};

#pragma unroll 1
  for (int t = 0; t < 512; ++t) {
    const int pb = t & 1;
    // prefetch t+1 (at t=511 reads harmlessly into dead theta space)
    unsigned short xan = xg[xb], xbn = xg[xb + 256];
    unsigned short cn = C2[cb + 256];

#pragma unroll
    for (int kt = 0; kt < 2; ++kt) {
      int ab = col * 264 + kt * 128 + (l >> 4) * 32;
      uint4 a0 = *(const uint4*)&hq[pb][ab];
      uint4 a1 = *(const uint4*)&hq[pb][ab + 16];
      i32x8 av;
      av[0] = (int)a0.x; av[1] = (int)a0.y; av[2] = (int)a0.z; av[3] = (int)a0.w;
      av[4] = (int)a1.x; av[5] = (int)a1.y; av[6] = (int)a1.z; av[7] = (int)a1.w;
#pragma unroll
      for (int nt = 0; nt < 2; ++nt)
#pragma unroll
        for (int g = 0; g < 4; ++g)
          acc[nt][g] = __builtin_amdgcn_mfma_scale_f32_16x16x128_f8f6f4(
              av, wreg[nt][g][kt], acc[nt][g], 0, 0, 0, 0x7F7F7F7F, 0, 0x7F7F7F7F);
    }

    // running sums -> per-step values; redistribute to 2 gates per lane
    float m0 = __uint_as_float(
        __builtin_amdgcn_permlane32_swap(__float_as_uint(acc[0][0][0]),
                                         __float_as_uint(acc[1][0][0]), false, false)[0]);
    float m1 = __uint_as_float(
        __builtin_amdgcn_permlane32_swap(__float_as_uint(acc[0][1][0]),
                                         __float_as_uint(acc[1][1][0]), false, false)[0]);
    float m2 = __uint_as_float(
        __builtin_amdgcn_permlane32_swap(__float_as_uint(acc[0][2][0]),
                                         __float_as_uint(acc[1][2][0]), false, false)[0]);
    float m3 = __uint_as_float(
        __builtin_amdgcn_permlane32_swap(__float_as_uint(acc[0][3][0]),
                                         __float_as_uint(acc[1][3][0]), false, false)[0]);
    float mm2 = __shfl_xor(m2, 16);
    float mm3 = __shfl_xor(m3, 16);
    float a_ = half ? mm2 : m0;
    float b_ = half ? mm3 : m1;
    float pa = a_ - SoldA;
    SoldA = a_;
    float pb_ = b_ - SoldB;
    SoldB = b_;

    float va = pa * fsa + bf2f(xac);
    float vb = pb_ * fsb + bf2f(xbc);
    // ra: sigm(va) on i-lanes, tanh(va) on g-lanes (branchless); rb: sigm(vb)
    float ra = AA * __fdividef(1.f, 1.f + __expf(-SS * va)) + BB;
    float rb = sigm(vb);
    // combine on g,o lanes: si, sf come from partner (lane^16)
    float si = __shfl_xor(ra, 16);
    float sf = __shfl_xor(rb, 16);
    float cv = sf * cst + si * ra;  // valid on g,o lanes (bounded garbage elsewhere)
    cst = cv;
    float th = tanh_(cv);
    float hv = rb * th;  // o * tanh(c)
    if (half) {
      h2[cb] = f2bf(hv * bf2f(cc));
      int pk = __builtin_amdgcn_cvt_pk_fp8_f32(hv, hv, 0, 0);
      hq[pb ^ 1][u] = (char)(pk & 255);
    }
    xac = xan;
    xbc = xbn;
    cc = cn;
    xb += 1024;
    cb += 256;
    __syncthreads();
  }
}

extern "C" void kernel_launch(void* const* d_in, const int* in_sizes, int n_in,
                              void* d_out, int out_size, void* d_ws, size_t ws_size,
                              hipStream_t stream) {
  const int* q = (const int*)d_in[0];
  const int* r = (const int*)d_in[1];
  const int* rg = (const int*)d_in[2];
  const int* sg = (const int*)d_in[3];
  const int* pc = (const int*)d_in[4];
  const int* srg = (const int*)d_in[5];
  const int* ssg = (const int*)d_in[6];
  const int* spc = (const int*)d_in[7];
  const float* E = (const float*)d_in[8];
  const float* Wc = (const float*)d_in[9];
  const float* Wih = (const float*)d_in[10];
  const float* Whh = (const float*)d_in[11];
  const float* bih = (const float*)d_in[12];
  const float* bhh = (const float*)d_in[13];
  const float* Wout = (const float*)d_in[14];
  const float* bout = (const float*)d_in[15];

  char* ws = (char*)d_ws;
  unsigned short* h2 = (unsigned short*)(ws);                // 64 MB
  unsigned short* Bpih = (unsigned short*)(ws + 67108864);   // 640 KB
  unsigned short* Bpout = (unsigned short*)(ws + 67764224);  // 1.25 MB
  long long* Wq = (long long*)(ws + 69074944);               // 256 KB
  float* fs = (float*)(ws + 69337088);                       // 4 KB
  int* combo = (int*)(ws + 69341184);                        // 512 KB
  int* combo2 = (int*)(ws + 69865472);                       // 512 KB (end 70389760)

  char* dout = (char*)d_out;
  unsigned short* xg = (unsigned short*)dout;                    // 256 MB (dead until final GEMM)
  unsigned short* theta = (unsigned short*)(dout + 268435456);   // 64 MB
  unsigned short* C2 = (unsigned short*)(dout + 335544320);      // 64 MB

  k_rowmax<<<1024, 64, 0, stream>>>(Whh, fs);
  k_pack_whh_mx<<<32, 256, 0, stream>>>(Whh, fs, Wq);
  k_pack_b<<<1280, 256, 0, stream>>>(Wih, Bpih, 63, 6);
  k_pack_b<<<2560, 256, 0, stream>>>(Wout, Bpout, 127, 7);
  k_theta<<<16384, 256, 0, stream>>>(q, r, rg, sg, pc, srg, ssg, spc, E, Wc, theta, C2, combo, combo2);
  k_gemm<1024, 0, 3><<<dim3(8, 1024), 256, 0, stream>>>(theta, Bpih, combo, bih, bhh, (void*)xg);
  k_lstm<<<256, 512, 0, stream>>>(xg, C2, Wq, fs, h2);
  k_gemm<2048, 1, 4><<<dim3(16, 1024), 256, 0, stream>>>(h2, Bpout, combo2, bout, nullptr, d_out);
}